// Round 1
// 426.339 us; speedup vs baseline: 1.0032x; 1.0032x over previous
//
#include <hip/hip_runtime.h>
#include <hip/hip_bf16.h>

// Downsample: ternary-quantized conv3x3 stride2 pad1, NCHW.
// x:(32,384,64,64) f32, w:(384,384,3,3) f32, bias:(384,) f32 -> out:(32,384,32,32) f32
// Implicit GEMM: M=32768 (n,oh,ow), N=384 (o), K=3456 ((kh,kw,c)), bf16 MFMA.
// Round 4: conv_gemm rebuilt as the 8-phase counted-vmcnt schedule (T3+T4+T5):
//   BM=128 x BNO=384 (full N), BK=64, 512 thr / 8 waves, 2x64KB LDS dbuf (128 KiB),
//   4 phases per K-step, half-tile prefetch order A0,B0,B1,A1 with counted
//   s_waitcnt vmcnt(6/4/-/4) (never 0 in the main loop), raw s_barrier +
//   sched_barrier(0) edges, s_setprio(1) around each 12-MFMA cluster.
//   Frag-register reuse: 20 ds_read_b128 per K-step (A halves reused across 2
//   phases, B halves live across the step). Peeled tail tile with vmcnt(3)/(0).
// Deterministic: no atomics anywhere.

#define CIN   384
#define HIN   64
#define WIN   64
#define OHW   32
#define KDIM  3456          // 9*384
#define NWELT 1327104       // 384*384*9
#define MDIM  32768         // 32*32*32
#define NT    54            // K-steps of 64

using bf16 = __hip_bfloat16;
typedef __attribute__((ext_vector_type(8))) short short8;   // MFMA A/B frag (8 bf16)
typedef __attribute__((ext_vector_type(4))) float floatx4;  // MFMA C/D frag
typedef __attribute__((ext_vector_type(2))) unsigned short ushort2v;

#define AS1 __attribute__((address_space(1)))
#define AS3 __attribute__((address_space(3)))
#define DMA16(g, l) __builtin_amdgcn_global_load_lds((const AS1 void*)(g), (AS3 void*)(l), 16, 0, 0)

// phase edge: counted vmem wait + raw barrier + hard scheduling fence.
// asm memory clobber pins LDS reads/DMA issues on their side of the edge;
// sched_barrier(0) stops loads hoisting above the s_barrier (rule 18).
#define EDGE(N) do { \
    asm volatile("s_waitcnt vmcnt(" #N ")" ::: "memory"); \
    __builtin_amdgcn_s_barrier(); \
    __builtin_amdgcn_sched_barrier(0); \
} while (0)

// ws layout (floats): [0]=alpha, [1]=thr, [2..64)=62 partials; f[16..20) is
// REUSED as a 16B zero region (written by absum_final AFTER consuming partials).
// bytes [256, 256+100663296): x_nhwc bf16 [32][64][64][384]
// bytes [256+100663296, +2654208): Wq bf16 [384][3456] (k=(kh*3+kw)*384+c)
#define NPART  62
#define ZG_F   16
#define XN_OFF 256
#define WQ_OFF (256 + 100663296)

// ---- Stage 1: fixed-slot partial sums of |w| (no atomics -> deterministic) ----
__global__ void absum_part(const float* __restrict__ w, float* __restrict__ ws) {
    const float4* w4 = (const float4*)w;
    float s = 0.f;
    for (int i = blockIdx.x * 256 + threadIdx.x; i < NWELT / 4; i += NPART * 256) {
        float4 v = w4[i];
        s += fabsf(v.x) + fabsf(v.y) + fabsf(v.z) + fabsf(v.w);
    }
    for (int off = 32; off; off >>= 1) s += __shfl_down(s, off, 64);
    __shared__ float red[4];
    if ((threadIdx.x & 63) == 0) red[threadIdx.x >> 6] = s;
    __syncthreads();
    if (threadIdx.x == 0) ws[2 + blockIdx.x] = red[0] + red[1] + red[2] + red[3];
}

// ---- Stage 2: fixed-order final reduction; also zero the DMA guard region ----
__global__ void absum_final(float* __restrict__ ws) {
    if (threadIdx.x == 0) {
        float s = 0.f;
        for (int i = 0; i < NPART; ++i) s += ws[2 + i];
        float alpha = s * (1.0f / NWELT);
        ws[0] = alpha;
        ws[1] = 1e-3f * alpha;
        ws[ZG_F + 0] = 0.f; ws[ZG_F + 1] = 0.f;   // 16B zero guard (partials dead now)
        ws[ZG_F + 2] = 0.f; ws[ZG_F + 3] = 0.f;
    }
}

// ---- Ternary quantize, output-indexed (coalesced 2B writes; reads are L2/L3-hot) ----
__global__ void quant_kernel(const float* __restrict__ w, const float* __restrict__ ws,
                             bf16* __restrict__ wq) {
    int j = blockIdx.x * 256 + threadIdx.x;   // j = o*3456 + (kh*3+kw)*384 + c
    if (j >= NWELT) return;
    float thr = ws[1];
    int o = j / KDIM;
    int rmd = j - o * KDIM;
    int khkw = rmd / 384;
    int c = rmd - khkw * 384;
    float v = w[((o * 384 + c) * 9) + khkw];
    float q = (v > thr) ? 1.f : ((v < -thr) ? -1.f : 0.f);
    wq[j] = __float2bfloat16(q);
}

// ---- NCHW f32 -> NHWC bf16. Block: 64c x 64w for one (n,h). grid=(2048, 6). ----
__global__ void nhwc_kernel(const float* __restrict__ x, bf16* __restrict__ xn) {
    int nh = blockIdx.x;
    int n = nh >> 6, h = nh & 63;
    int c0 = blockIdx.y * 64;
    __shared__ bf16 tile[64][66];   // stride 66: column reads ~conflict-free (33c banks)
    const float* src = x + ((n * CIN + c0) * HIN + h) * WIN;  // c-row stride 4096 floats
    for (int i = 0; i < 4; ++i) {
        int s = threadIdx.x + i * 256;     // [0,1024): 64c x 16 float4
        int cl = s >> 4, w4 = (s & 15) * 4;
        float4 v = *(const float4*)(src + cl * 4096 + w4);
        bf16 t0[2], t1[2];
        t0[0] = __float2bfloat16(v.x); t0[1] = __float2bfloat16(v.y);
        t1[0] = __float2bfloat16(v.z); t1[1] = __float2bfloat16(v.w);
        *(ushort2v*)&tile[cl][w4]     = *(ushort2v*)t0;   // 4B aligned
        *(ushort2v*)&tile[cl][w4 + 2] = *(ushort2v*)t1;
    }
    __syncthreads();
    bf16* dst = xn + ((size_t)(n * HIN + h) * WIN) * CIN + c0;
    for (int i = 0; i < 2; ++i) {
        int q = threadIdx.x + i * 256;     // [0,512): 64w x 8 c-octets
        int wc = q >> 3, c8 = (q & 7) * 8;
        bf16 tmp[8];
        #pragma unroll
        for (int j = 0; j < 8; ++j) tmp[j] = tile[c8 + j][wc];
        *(short8*)(dst + (size_t)wc * CIN + c8) = *(short8*)tmp;
    }
}

// ---- GEMM: D[o][m] = sum_k Wq[o][k] * X[m][k]. A=Wq (384 rows), B=X (128 rows). ----
// 8-phase schedule. Halves: A0=o[0,192) A1=o[192,384); B0=m[0,64) B1=m[64,128).
// Wave wv: io=wv&3 (o-pos), im=wv>>2 (m-pos). Wave frags interleave halves:
//   o = h*192 + io*48 + fo*16   (fo<3, per A-half)   -> acc rows 0..5
//   m = h*64  + im*32 + fm*16   (fm<2, per B-half)   -> acc cols 0..3
// so each phase's quadrant touches exactly one A-half + one B-half for ALL waves.
// Phase consumption: P1(A0,B0) P2(A0,B1) P3(A1,B1) P4(A1,B0-reused-in-regs).
// Stage (tile t+1, during t): P1:A0(3 DMA) P2:B0(1) P3:B1(1) P4:A1(3).
// Counted waits (FIFO retirement, per-wave): P1 vmcnt(6) -> B1_t landed;
// P2 vmcnt(4) -> A1_t; P3 none; P4 vmcnt(4) -> A0_{t+1},B0_{t+1}.
// LDS layout per row (64 k-elems, 128B, unpadded): slot(r,oct) at r*128 +
// (oct^(r&7))*16 -- DMA dest stays linear (lane*16), global src pre-swizzled
// via g=(lane&7)^(lane>>3); ds_read folds to <=2-way bank alias.
#define BM  128

__global__ __launch_bounds__(512, 2) void conv_gemm(const bf16* __restrict__ xn,
                                                    const bf16* __restrict__ wq,
                                                    const float* __restrict__ ws,
                                                    const float* __restrict__ bias,
                                                    float* __restrict__ out,
                                                    const bf16* __restrict__ zg) {
    __shared__ __align__(16) bf16 lW[2][384 * 64];   // 96 KiB
    __shared__ __align__(16) bf16 lX[2][128 * 64];   // 32 KiB
    const int m_base = blockIdx.x * BM;              // 256 blocks = 1/CU
    const int tid = threadIdx.x;
    const int lane = tid & 63;
    const int wv = tid >> 6;          // 0..7
    const int io = wv & 3;            // o wave-position (x48 per half)
    const int im = wv >> 2;           // m wave-position (x32 per half)
    const int g = (lane & 7) ^ (lane >> 3);          // pre-swizzled global octet

    // ---- staging descriptors ----
    const bf16* pw[2][3];             // W: 2 halves x 3 calls (8 rows each)
    int wLoff[2][3];
    #pragma unroll
    for (int h = 0; h < 2; ++h)
        #pragma unroll
        for (int j = 0; j < 3; ++j) {
            int rr = h * 192 + wv * 24 + j * 8;
            pw[h][j] = wq + (size_t)(rr + (lane >> 3)) * KDIM + g * 8;
            wLoff[h][j] = rr * 64;
        }
    const bf16* pxn[2];               // X: 2 halves x 1 call
    int oh2[2], ow2[2], xLoff[2];
    #pragma unroll
    for (int h = 0; h < 2; ++h) {
        int rr = h * 64 + wv * 8;
        int m = m_base + rr + (lane >> 3);
        int n = m >> 10, oh = (m >> 5) & 31, ow = m & 31;
        pxn[h] = xn + (size_t)n * (HIN * WIN * CIN) + g * 8;
        oh2[h] = 2 * oh - 1;
        ow2[h] = 2 * ow - 1;
        xLoff[h] = rr * 64;
    }

    // ---- ds_read offsets (element units) ----
    const int l15 = lane & 15, quad = lane >> 4, l7 = lane & 7;
    const int octA = (quad ^ l7) * 8;         // ks=0 slot
    const int octB = ((4 + quad) ^ l7) * 8;   // ks=1 slot
    int aoff[2][3], boff[2][2];
    #pragma unroll
    for (int h = 0; h < 2; ++h)
        #pragma unroll
        for (int fo = 0; fo < 3; ++fo)
            aoff[h][fo] = (h * 192 + io * 48 + fo * 16 + l15) * 64;
    #pragma unroll
    for (int h = 0; h < 2; ++h)
        #pragma unroll
        for (int fm = 0; fm < 2; ++fm)
            boff[h][fm] = (h * 64 + im * 32 + fm * 16 + l15) * 64;

    floatx4 acc[6][4];
    #pragma unroll
    for (int i = 0; i < 6; ++i)
        #pragma unroll
        for (int j = 0; j < 4; ++j)
            acc[i][j] = (floatx4){0.f, 0.f, 0.f, 0.f};

    // ---- prologue: stage tile 0 into buf 0, order A0,B0 | B1,A1; leave 4 in flight ----
    {
        #pragma unroll
        for (int j = 0; j < 3; ++j) DMA16(pw[0][j], &lW[0][wLoff[0][j]]);     // A0
        {
            int ih = oh2[0], iw = ow2[0];   // khkw=0 -> kh=kw=0
            const bf16* p = (ih >= 0 && iw >= 0) ? pxn[0] + (ih * WIN + iw) * CIN : zg;
            DMA16(p, &lX[0][xLoff[0]]);                                        // B0
        }
        {
            int ih = oh2[1], iw = ow2[1];
            const bf16* p = (ih >= 0 && iw >= 0) ? pxn[1] + (ih * WIN + iw) * CIN : zg;
            DMA16(p, &lX[0][xLoff[1]]);                                        // B1
        }
        #pragma unroll
        for (int j = 0; j < 3; ++j) DMA16(pw[1][j], &lW[0][wLoff[1][j]]);     // A1
        EDGE(4);   // A0,B0 landed (all waves); B1,A1 still in flight
    }

    short8 af[2][3], bfl[2][2], bfh[2][2];

    for (int t = 0; t < NT - 1; ++t) {
        bf16* lWc = lW[t & 1];
        bf16* lXc = lX[t & 1];
        bf16* lWn = lW[(t & 1) ^ 1];
        bf16* lXn = lX[(t & 1) ^ 1];
        // next-step (s = t+1) staging addresses
        const int s = t + 1;
        const int kk = s / 6, cs = s - kk * 6;
        const int kh = kk / 3, kw = kk - kh * 3;
        const int ws64 = s * 64;
        const bf16* pxs[2];
        #pragma unroll
        for (int h = 0; h < 2; ++h) {
            int ih = oh2[h] + kh, iw = ow2[h] + kw;
            pxs[h] = (ih >= 0 && iw >= 0) ? pxn[h] + (ih * WIN + iw) * CIN + cs * 64 : zg;
        }

        // ---- P1: read af(A0)+bfl(B0); stage A0_{t+1}; MFMA rows0-2 x cols0-1 ----
        #pragma unroll
        for (int fo = 0; fo < 3; ++fo) {
            af[0][fo] = *(const short8*)(lWc + aoff[0][fo] + octA);
            af[1][fo] = *(const short8*)(lWc + aoff[0][fo] + octB);
        }
        #pragma unroll
        for (int fm = 0; fm < 2; ++fm) {
            bfl[0][fm] = *(const short8*)(lXc + boff[0][fm] + octA);
            bfl[1][fm] = *(const short8*)(lXc + boff[0][fm] + octB);
        }
        #pragma unroll
        for (int j = 0; j < 3; ++j) DMA16(pw[0][j] + ws64, lWn + wLoff[0][j]);
        EDGE(6);   // B1_t landed
        __builtin_amdgcn_s_setprio(1);
        #pragma unroll
        for (int ks = 0; ks < 2; ++ks)
            #pragma unroll
            for (int fo = 0; fo < 3; ++fo)
                #pragma unroll
                for (int fm = 0; fm < 2; ++fm)
                    acc[fo][fm] = __builtin_amdgcn_mfma_f32_16x16x32_bf16(
                        af[ks][fo], bfl[ks][fm], acc[fo][fm], 0, 0, 0);
        __builtin_amdgcn_s_setprio(0);

        // ---- P2: read bfh(B1); stage B0_{t+1}; MFMA rows0-2 x cols2-3 ----
        #pragma unroll
        for (int fm = 0; fm < 2; ++fm) {
            bfh[0][fm] = *(const short8*)(lXc + boff[1][fm] + octA);
            bfh[1][fm] = *(const short8*)(lXc + boff[1][fm] + octB);
        }
        DMA16(pxs[0], lXn + xLoff[0]);
        EDGE(4);   // A1_t landed
        __builtin_amdgcn_s_setprio(1);
        #pragma unroll
        for (int ks = 0; ks < 2; ++ks)
            #pragma unroll
            for (int fo = 0; fo < 3; ++fo)
                #pragma unroll
                for (int fm = 0; fm < 2; ++fm)
                    acc[fo][2 + fm] = __builtin_amdgcn_mfma_f32_16x16x32_bf16(
                        af[ks][fo], bfh[ks][fm], acc[fo][2 + fm], 0, 0, 0);
        __builtin_amdgcn_s_setprio(0);

        // ---- P3: read af(A1) (overwrite); stage B1_{t+1}; MFMA rows3-5 x cols2-3 ----
        #pragma unroll
        for (int fo = 0; fo < 3; ++fo) {
            af[0][fo] = *(const short8*)(lWc + aoff[1][fo] + octA);
            af[1][fo] = *(const short8*)(lWc + aoff[1][fo] + octB);
        }
        DMA16(pxs[1], lXn + xLoff[1]);
        // no edge: A1_t guaranteed by P2's edge; next consumer barrier is P4's.
        __builtin_amdgcn_s_setprio(1);
        #pragma unroll
        for (int ks = 0; ks < 2; ++ks)
            #pragma unroll
            for (int fo = 0; fo < 3; ++fo)
                #pragma unroll
                for (int fm = 0; fm < 2; ++fm)
                    acc[3 + fo][2 + fm] = __builtin_amdgcn_mfma_f32_16x16x32_bf16(
                        af[ks][fo], bfh[ks][fm], acc[3 + fo][2 + fm], 0, 0, 0);
        __builtin_amdgcn_s_setprio(0);

        // ---- P4: stage A1_{t+1}; MFMA rows3-5 x cols0-1 (bfl reused from regs) ----
        #pragma unroll
        for (int j = 0; j < 3; ++j) DMA16(pw[1][j] + ws64, lWn + wLoff[1][j]);
        EDGE(4);   // A0_{t+1},B0_{t+1} landed -> next tile's P1 may read
        __builtin_amdgcn_s_setprio(1);
        #pragma unroll
        for (int ks = 0; ks < 2; ++ks)
            #pragma unroll
            for (int fo = 0; fo < 3; ++fo)
                #pragma unroll
                for (int fm = 0; fm < 2; ++fm)
                    acc[3 + fo][fm] = __builtin_amdgcn_mfma_f32_16x16x32_bf16(
                        af[ks][fo], bfl[ks][fm], acc[3 + fo][fm], 0, 0, 0);
        __builtin_amdgcn_s_setprio(0);
    }

    // ---- peeled tail tile (t = 53, buf 1): no stages, tight waits ----
    {
        bf16* lWc = lW[1];
        bf16* lXc = lX[1];
        // P1
        #pragma unroll
        for (int fo = 0; fo < 3; ++fo) {
            af[0][fo] = *(const short8*)(lWc + aoff[0][fo] + octA);
            af[1][fo] = *(const short8*)(lWc + aoff[0][fo] + octB);
        }
        #pragma unroll
        for (int fm = 0; fm < 2; ++fm) {
            bfl[0][fm] = *(const short8*)(lXc + boff[0][fm] + octA);
            bfl[1][fm] = *(const short8*)(lXc + boff[0][fm] + octB);
        }
        EDGE(3);   // B1_53 landed
        __builtin_amdgcn_s_setprio(1);
        #pragma unroll
        for (int ks = 0; ks < 2; ++ks)
            #pragma unroll
            for (int fo = 0; fo < 3; ++fo)
                #pragma unroll
                for (int fm = 0; fm < 2; ++fm)
                    acc[fo][fm] = __builtin_amdgcn_mfma_f32_16x16x32_bf16(
                        af[ks][fo], bfl[ks][fm], acc[fo][fm], 0, 0, 0);
        __builtin_amdgcn_s_setprio(0);
        // P2
        #pragma unroll
        for (int fm = 0; fm < 2; ++fm) {
            bfh[0][fm] = *(const short8*)(lXc + boff[1][fm] + octA);
            bfh[1][fm] = *(const short8*)(lXc + boff[1][fm] + octB);
        }
        EDGE(0);   // A1_53 landed
        __builtin_amdgcn_s_setprio(1);
        #pragma unroll
        for (int ks = 0; ks < 2; ++ks)
            #pragma unroll
            for (int fo = 0; fo < 3; ++fo)
                #pragma unroll
                for (int fm = 0; fm < 2; ++fm)
                    acc[fo][2 + fm] = __builtin_amdgcn_mfma_f32_16x16x32_bf16(
                        af[ks][fo], bfh[ks][fm], acc[fo][2 + fm], 0, 0, 0);
        __builtin_amdgcn_s_setprio(0);
        // P3
        #pragma unroll
        for (int fo = 0; fo < 3; ++fo) {
            af[0][fo] = *(const short8*)(lWc + aoff[1][fo] + octA);
            af[1][fo] = *(const short8*)(lWc + aoff[1][fo] + octB);
        }
        __builtin_amdgcn_s_setprio(1);
        #pragma unroll
        for (int ks = 0; ks < 2; ++ks)
            #pragma unroll
            for (int fo = 0; fo < 3; ++fo)
                #pragma unroll
                for (int fm = 0; fm < 2; ++fm)
                    acc[3 + fo][2 + fm] = __builtin_amdgcn_mfma_f32_16x16x32_bf16(
                        af[ks][fo], bfh[ks][fm], acc[3 + fo][2 + fm], 0, 0, 0);
        __builtin_amdgcn_s_setprio(0);
        // P4
        __builtin_amdgcn_s_setprio(1);
        #pragma unroll
        for (int ks = 0; ks < 2; ++ks)
            #pragma unroll
            for (int fo = 0; fo < 3; ++fo)
                #pragma unroll
                for (int fm = 0; fm < 2; ++fm)
                    acc[3 + fo][fm] = __builtin_amdgcn_mfma_f32_16x16x32_bf16(
                        af[ks][fo], bfl[ks][fm], acc[3 + fo][fm], 0, 0, 0);
        __builtin_amdgcn_s_setprio(0);
    }

    // ---- epilogue: D row = o (quad*4+reg), col = m (lane&15) -> coalesced along ow ----
    float alpha = ws[0];
    #pragma unroll
    for (int i = 0; i < 6; ++i) {
        int o0 = (i / 3) * 192 + io * 48 + (i % 3) * 16 + quad * 4;
        #pragma unroll
        for (int j = 0; j < 4; ++j) {
            int m = m_base + (j >> 1) * 64 + im * 32 + (j & 1) * 16 + l15;
            int n = m >> 10, ohh = (m >> 5) & 31, oww = m & 31;
            #pragma unroll
            for (int r = 0; r < 4; ++r) {
                int o = o0 + r;
                out[((n * 384 + o) * OHW + ohh) * OHW + oww] = alpha * acc[i][j][r] + bias[o];
            }
        }
    }
}

extern "C" void kernel_launch(void* const* d_in, const int* in_sizes, int n_in,
                              void* d_out, int out_size, void* d_ws, size_t ws_size,
                              hipStream_t stream) {
    (void)in_sizes; (void)n_in; (void)out_size; (void)ws_size;
    const float* x    = (const float*)d_in[0];
    const float* w    = (const float*)d_in[1];
    const float* bias = (const float*)d_in[2];
    float* out = (float*)d_out;
    float* wsf = (float*)d_ws;
    bf16* xn = (bf16*)((char*)d_ws + XN_OFF);
    bf16* wq = (bf16*)((char*)d_ws + WQ_OFF);
    const bf16* zg = (const bf16*)(wsf + ZG_F);

    absum_part<<<NPART, 256, 0, stream>>>(w, wsf);
    absum_final<<<1, 64, 0, stream>>>(wsf);
    quant_kernel<<<(NWELT + 255) / 256, 256, 0, stream>>>(w, wsf, wq);
    nhwc_kernel<<<dim3(2048, 6), 256, 0, stream>>>(x, xn);
    conv_gemm<<<dim3(MDIM / BM, 1), 512, 0, stream>>>(xn, wq, wsf, bias, out, zg);
}